// Round 1
// baseline (4767.992 us; speedup 1.0000x reference)
//
#include <hip/hip_runtime.h>
#include <cmath>

#define N_NODES 50000
#define N_EDGES 100000
#define HALF_N  25000
#define DIM     256
#define FFDIM   1024
#define NDEPTH  2
#define FF_CHUNK 6250

__device__ __forceinline__ float wave_sum(float v) {
  v += __shfl_xor(v, 1);
  v += __shfl_xor(v, 2);
  v += __shfl_xor(v, 4);
  v += __shfl_xor(v, 8);
  v += __shfl_xor(v, 16);
  v += __shfl_xor(v, 32);
  return v;
}

// ---------------- LayerNorm (wave per row, 256 cols) ----------------
__global__ void ln_kernel(const float* __restrict__ in, const float* __restrict__ g,
                          const float* __restrict__ b, float* __restrict__ out, int rows) {
  int row = blockIdx.x * 4 + (threadIdx.x >> 6);
  if (row >= rows) return;
  int lane = threadIdx.x & 63;
  float4 x = reinterpret_cast<const float4*>(in + (size_t)row * DIM)[lane];
  float mu = wave_sum(x.x + x.y + x.z + x.w) * (1.0f / DIM);
  float d0 = x.x - mu, d1 = x.y - mu, d2 = x.z - mu, d3 = x.w - mu;
  float var = wave_sum(d0*d0 + d1*d1 + d2*d2 + d3*d3) * (1.0f / DIM);
  float r = rsqrtf(var + 1e-5f);
  float4 gv = reinterpret_cast<const float4*>(g)[lane];
  float4 bv = reinterpret_cast<const float4*>(b)[lane];
  float4 o;
  o.x = d0 * r * gv.x + bv.x;
  o.y = d1 * r * gv.y + bv.y;
  o.z = d2 * r * gv.z + bv.z;
  o.w = d3 * r * gv.w + bv.w;
  reinterpret_cast<float4*>(out + (size_t)row * DIM)[lane] = o;
}

// ---------------- fp32 tiled GEMM: C = A[M,K] @ W[K,Nc] (+bias) ----------------
// grid (Nc/64, ceil(M/64)), block 256. EPI: 0 = bias, 1 = bias + exact GELU.
template<int EPI>
__global__ void gemm64(const float* __restrict__ A, const float* __restrict__ W,
                       const float* __restrict__ bias, float* __restrict__ C,
                       int M, int K, int Nc) {
  __shared__ float As[16][68];
  __shared__ float Ws[16][68];
  int tid = threadIdx.x;
  int tx = tid & 15, ty = tid >> 4;
  int row0 = blockIdx.y * 64, col0 = blockIdx.x * 64;
  float acc[4][4] = {};
  for (int k0 = 0; k0 < K; k0 += 16) {
#pragma unroll
    for (int i = 0; i < 4; ++i) {
      int idx = tid + i * 256;
      int r = idx >> 4, c = idx & 15;           // A tile 64x16
      int gr = row0 + r;
      As[c][r] = (gr < M) ? A[(size_t)gr * K + k0 + c] : 0.0f;
      int wr = idx >> 6, wc = idx & 63;          // W tile 16x64
      Ws[wr][wc] = W[(size_t)(k0 + wr) * Nc + col0 + wc];
    }
    __syncthreads();
#pragma unroll
    for (int kk = 0; kk < 16; ++kk) {
      float a[4], bb[4];
#pragma unroll
      for (int j = 0; j < 4; ++j) a[j] = As[kk][ty * 4 + j];
#pragma unroll
      for (int j = 0; j < 4; ++j) bb[j] = Ws[kk][tx * 4 + j];
#pragma unroll
      for (int i = 0; i < 4; ++i)
#pragma unroll
        for (int j = 0; j < 4; ++j) acc[i][j] += a[i] * bb[j];
    }
    __syncthreads();
  }
#pragma unroll
  for (int i = 0; i < 4; ++i) {
    int gr = row0 + ty * 4 + i;
    if (gr >= M) continue;
#pragma unroll
    for (int j = 0; j < 4; ++j) {
      int col = col0 + tx * 4 + j;
      float v = acc[i][j] + (bias ? bias[col] : 0.0f);
      if (EPI == 1) v = 0.5f * v * (1.0f + erff(v * 0.70710678118654752f));
      C[(size_t)gr * Nc + col] = v;
    }
  }
}

// ---------------- fold xeA into k and v (kv layout: [HALF][512]) ----------------
__global__ void fold_ea(float* __restrict__ kv, const float* __restrict__ eA) {
  size_t idx = (size_t)blockIdx.x * 256 + threadIdx.x;
  if (idx >= (size_t)HALF_N * 64) return;
  size_t row = idx >> 6; int c = idx & 63;
  float4 a = reinterpret_cast<const float4*>(eA)[row * 64 + c];
  float4* kp = reinterpret_cast<float4*>(kv) + row * 128 + c;
  float4 k = kp[0];
  k.x += a.x; k.y += a.y; k.z += a.z; k.w += a.w;
  kp[0] = k;
  float4 v = kp[64];
  v.x += a.x; v.y += a.y; v.z += a.z; v.w += a.w;
  kp[64] = v;
}

__device__ __forceinline__ unsigned f2key(float f) {
  unsigned u = __float_as_uint(f);
  return (u & 0x80000000u) ? ~u : (u | 0x80000000u);
}
__device__ __forceinline__ float key2f(unsigned key) {
  unsigned u = (key & 0x80000000u) ? (key & 0x7FFFFFFFu) : ~key;
  return __uint_as_float(u);
}

// ---------------- edge pass A: sim + segment max (wave per edge) ----------------
__global__ void edge_sim(const int* __restrict__ ei, const float* __restrict__ q,
                         const float* __restrict__ kv, const float* __restrict__ eB,
                         float* __restrict__ sim, unsigned* __restrict__ smax) {
  int e = blockIdx.x * 4 + (threadIdx.x >> 6);
  if (e >= N_EDGES) return;
  int lane = threadIdx.x & 63;
  int s = ei[e], d = ei[N_EDGES + e];
  float4 qv = reinterpret_cast<const float4*>(q + (size_t)d * DIM)[lane];
  float4 kv4 = reinterpret_cast<const float4*>(kv + (size_t)s * 512)[lane];
  float4 ev = reinterpret_cast<const float4*>(eB + (size_t)d * DIM)[lane];
  float p = qv.x * (kv4.x + ev.x) + qv.y * (kv4.y + ev.y) +
            qv.z * (kv4.z + ev.z) + qv.w * (kv4.w + ev.w);
  p += __shfl_xor(p, 1); p += __shfl_xor(p, 2);
  p += __shfl_xor(p, 4); p += __shfl_xor(p, 8);
  if ((lane & 15) == 0) {
    int h = lane >> 4;
    float sv = p * 0.125f;  // DH^-0.5
    sim[(size_t)e * 4 + h] = sv;
    atomicMax(&smax[(size_t)d * 4 + h], f2key(sv));
  }
}

// ---------------- edge pass B: exp + scatter-add denom, aggU ----------------
__global__ void edge_agg(const int* __restrict__ ei, const float* __restrict__ kv,
                         const float* __restrict__ eB, const float* __restrict__ sim,
                         const unsigned* __restrict__ smax, float* __restrict__ denom,
                         float* __restrict__ aggU) {
  int e = blockIdx.x * 4 + (threadIdx.x >> 6);
  if (e >= N_EDGES) return;
  int lane = threadIdx.x & 63;
  int s = ei[e], d = ei[N_EDGES + e];
  int h = lane >> 4;
  float m = key2f(smax[(size_t)d * 4 + h]);
  float ez = expf(sim[(size_t)e * 4 + h] - m);
  float4 vv = reinterpret_cast<const float4*>(kv + (size_t)s * 512 + 256)[lane];
  float4 ev = reinterpret_cast<const float4*>(eB + (size_t)d * DIM)[lane];
  float* dst = aggU + (size_t)d * DIM + lane * 4;
  unsafeAtomicAdd(dst + 0, ez * (vv.x + ev.x));
  unsafeAtomicAdd(dst + 1, ez * (vv.y + ev.y));
  unsafeAtomicAdd(dst + 2, ez * (vv.z + ev.z));
  unsafeAtomicAdd(dst + 3, ez * (vv.w + ev.w));
  if ((lane & 15) == 0) unsafeAtomicAdd(&denom[(size_t)d * 4 + h], ez);
}

// ---------------- normalize agg (guard empty segments) ----------------
__global__ void norm_agg(float* __restrict__ aggU, const float* __restrict__ denom) {
  size_t idx = (size_t)blockIdx.x * 256 + threadIdx.x;
  if (idx >= (size_t)HALF_N * 64) return;
  size_t row = idx >> 6; int c = idx & 63;
  float dn = denom[row * 4 + (c >> 4)];
  float inv = (dn > 0.0f) ? (1.0f / dn) : 0.0f;
  float4* p = reinterpret_cast<float4*>(aggU) + row * 64 + c;
  float4 v = *p;
  v.x *= inv; v.y *= inv; v.z *= inv; v.w *= inv;
  *p = v;
}

// ---------------- gated residual (wave per row) ----------------
// x-source: xin[r] for r < xvr, else fb (broadcast bias). nodes updated in place.
__global__ void gated_res(const float* __restrict__ xin, const float* __restrict__ fb,
                          float* __restrict__ nodes, const float* __restrict__ w,
                          int rows, int xvr) {
  int r = blockIdx.x * 4 + (threadIdx.x >> 6);
  if (r >= rows) return;
  int lane = threadIdx.x & 63;
  float4 xv = (r < xvr) ? reinterpret_cast<const float4*>(xin + (size_t)r * DIM)[lane]
                        : reinterpret_cast<const float4*>(fb)[lane];
  float4 rv = reinterpret_cast<const float4*>(nodes + (size_t)r * DIM)[lane];
  float4 w0 = reinterpret_cast<const float4*>(w)[lane];
  float4 w1 = reinterpret_cast<const float4*>(w + 256)[lane];
  float4 w2 = reinterpret_cast<const float4*>(w + 512)[lane];
  float p = xv.x * (w0.x + w2.x) + rv.x * (w1.x - w2.x)
          + xv.y * (w0.y + w2.y) + rv.y * (w1.y - w2.y)
          + xv.z * (w0.z + w2.z) + rv.z * (w1.z - w2.z)
          + xv.w * (w0.w + w2.w) + rv.w * (w1.w - w2.w);
  p = wave_sum(p);
  float gate = 1.0f / (1.0f + expf(-p));
  float4 o;
  o.x = xv.x * gate + rv.x * (1.0f - gate);
  o.y = xv.y * gate + rv.y * (1.0f - gate);
  o.z = xv.z * gate + rv.z * (1.0f - gate);
  o.w = xv.w * gate + rv.w * (1.0f - gate);
  reinterpret_cast<float4*>(nodes + (size_t)r * DIM)[lane] = o;
}

// ---------------- final projection + output scatter ----------------
__global__ void out_kernel(const float* __restrict__ nodes, const float* __restrict__ Wout,
                           const float* __restrict__ bout, float* __restrict__ out) {
  int r = blockIdx.x * 4 + (threadIdx.x >> 6);
  if (r >= N_NODES) return;
  int lane = threadIdx.x & 63;
  float4 nv = reinterpret_cast<const float4*>(nodes + (size_t)r * DIM)[lane];
  float4 wv = reinterpret_cast<const float4*>(Wout)[lane];
  float p = nv.x * wv.x + nv.y * wv.y + nv.z * wv.z + nv.w * wv.w;
  p = wave_sum(p);
  if (lane == 0) {
    float z = p + bout[0];
    if (r < HALF_N) {
      out[HALF_N + r] = z;                 // z_old slot
    } else {
      int j = r - HALF_N;
      out[j] = z;                          // z_new.reshape(-1)
      out[2 * HALF_N + j] = z;             // z_new slot
    }
  }
}

extern "C" void kernel_launch(void* const* d_in, const int* in_sizes, int n_in,
                              void* d_out, int out_size, void* d_ws, size_t ws_size,
                              hipStream_t stream) {
  const float* x     = (const float*)d_in[0];
  const int*   ei    = (const int*)d_in[1];
  const float* ln1_g = (const float*)d_in[2];
  const float* ln1_b = (const float*)d_in[3];
  const float* Wq    = (const float*)d_in[4];
  const float* bq    = (const float*)d_in[5];
  const float* Wkv   = (const float*)d_in[6];
  const float* bkv   = (const float*)d_in[7];
  const float* We    = (const float*)d_in[8];
  const float* be    = (const float*)d_in[9];
  const float* Wo    = (const float*)d_in[10];
  const float* bo    = (const float*)d_in[11];
  const float* g_attn= (const float*)d_in[12];
  const float* ln2_g = (const float*)d_in[13];
  const float* ln2_b = (const float*)d_in[14];
  const float* W1    = (const float*)d_in[15];
  const float* b1    = (const float*)d_in[16];
  const float* W2    = (const float*)d_in[17];
  const float* b2    = (const float*)d_in[18];
  const float* g_ff  = (const float*)d_in[19];
  const float* Wout  = (const float*)d_in[20];
  const float* bout  = (const float*)d_in[21];
  float* out = (float*)d_out;

  // workspace layout (floats)
  float* ws = (float*)d_ws;
  size_t off = 0;
  float* nodes = ws + off; off += (size_t)N_NODES * DIM;   // 12.8M
  float* xn    = ws + off; off += (size_t)N_NODES * DIM;   // 12.8M
  float* qb    = ws + off; off += (size_t)HALF_N * DIM;    // 6.4M (also attn_out)
  float* kvb   = ws + off; off += (size_t)HALF_N * 512;    // 12.8M
  float* eA    = ws + off; off += (size_t)HALF_N * DIM;    // 6.4M (also FF out)
  float* eB    = ws + off; off += (size_t)HALF_N * DIM;    // 6.4M
  float* sim   = ws + off; off += (size_t)N_EDGES * 4;     // 0.4M
  float* smaxf = ws + off; off += (size_t)HALF_N * 4;      // 0.1M
  float* denom = ws + off; off += (size_t)HALF_N * 4;      // 0.1M
  float* aggU  = ws + off; off += (size_t)HALF_N * DIM;    // 6.4M (also FF hidden)
  unsigned* smax = (unsigned*)smaxf;
  float* hbuf = aggU;   // FF hidden: FF_CHUNK*1024 = 6.4M floats, aliases aggU
  float* fbuf = eA;     // FF out:    FF_CHUNK*256  = 1.6M floats, aliases eA

  hipMemcpyAsync(nodes, x, (size_t)N_NODES * DIM * sizeof(float),
                 hipMemcpyDeviceToDevice, stream);

  for (int l = 0; l < NDEPTH; ++l) {
    const float* Wq_l  = Wq  + (size_t)l * DIM * DIM;
    const float* Wkv_l = Wkv + (size_t)l * DIM * 512;
    const float* We_l  = We  + (size_t)l * 512 * DIM;
    const float* Wo_l  = Wo  + (size_t)l * DIM * DIM;
    const float* W1_l  = W1  + (size_t)l * DIM * FFDIM;
    const float* W2_l  = W2  + (size_t)l * FFDIM * DIM;

    // LN1 (only HALF rows feed q/k/v)
    ln_kernel<<<(HALF_N + 3) / 4, 256, 0, stream>>>(nodes, ln1_g + l * DIM, ln1_b + l * DIM, xn, HALF_N);
    // q = xn @ Wq + bq
    gemm64<0><<<dim3(4, (HALF_N + 63) / 64), 256, 0, stream>>>(xn, Wq_l, bq + l * DIM, qb, HALF_N, DIM, DIM);
    // kv = xn @ Wkv + bkv
    gemm64<0><<<dim3(8, (HALF_N + 63) / 64), 256, 0, stream>>>(xn, Wkv_l, bkv + l * 512, kvb, HALF_N, DIM, 512);
    // edge proj: xeA = x @ We_top ; xeB = x @ We_bot + be   (uses ORIGINAL x)
    gemm64<0><<<dim3(4, (HALF_N + 63) / 64), 256, 0, stream>>>(x, We_l, nullptr, eA, HALF_N, DIM, DIM);
    gemm64<0><<<dim3(4, (HALF_N + 63) / 64), 256, 0, stream>>>(x, We_l + (size_t)DIM * DIM, be + l * DIM, eB, HALF_N, DIM, DIM);
    // k += xeA ; v += xeA
    fold_ea<<<(HALF_N * 64 + 255) / 256, 256, 0, stream>>>(kvb, eA);

    hipMemsetAsync(smax, 0, (size_t)HALF_N * 4 * sizeof(unsigned), stream);
    hipMemsetAsync(denom, 0, (size_t)HALF_N * 4 * sizeof(float), stream);
    hipMemsetAsync(aggU, 0, (size_t)HALF_N * DIM * sizeof(float), stream);

    edge_sim<<<(N_EDGES + 3) / 4, 256, 0, stream>>>(ei, qb, kvb, eB, sim, smax);
    edge_agg<<<(N_EDGES + 3) / 4, 256, 0, stream>>>(ei, kvb, eB, sim, smax, denom, aggU);
    norm_agg<<<(HALF_N * 64 + 255) / 256, 256, 0, stream>>>(aggU, denom);

    // attn_out = agg @ Wo + bo  (into qb)
    gemm64<0><<<dim3(4, (HALF_N + 63) / 64), 256, 0, stream>>>(aggU, Wo_l, bo + l * DIM, qb, HALF_N, DIM, DIM);
    // gated residual (rows >= HALF use attn_out = bo)
    gated_res<<<(N_NODES + 3) / 4, 256, 0, stream>>>(qb, bo + l * DIM, nodes, g_attn + l * 768, N_NODES, HALF_N);

    // LN2 over all rows
    ln_kernel<<<(N_NODES + 3) / 4, 256, 0, stream>>>(nodes, ln2_g + l * DIM, ln2_b + l * DIM, xn, N_NODES);

    // FF in row chunks: h = gelu(xn@W1+b1); f = h@W2+b2; gated residual
    for (int c = 0; c < N_NODES / FF_CHUNK; ++c) {
      int row0 = c * FF_CHUNK;
      gemm64<1><<<dim3(16, (FF_CHUNK + 63) / 64), 256, 0, stream>>>(xn + (size_t)row0 * DIM, W1_l, b1 + l * FFDIM, hbuf, FF_CHUNK, DIM, FFDIM);
      gemm64<0><<<dim3(4, (FF_CHUNK + 63) / 64), 256, 0, stream>>>(hbuf, W2_l, b2 + l * DIM, fbuf, FF_CHUNK, FFDIM, DIM);
      gated_res<<<(FF_CHUNK + 3) / 4, 256, 0, stream>>>(fbuf, nullptr, nodes + (size_t)row0 * DIM, g_ff + l * 768, FF_CHUNK, FF_CHUNK);
    }
  }

  out_kernel<<<(N_NODES + 3) / 4, 256, 0, stream>>>(nodes, Wout, bout, out);
}

// Round 2
// 1110.602 us; speedup vs baseline: 4.2932x; 4.2932x over previous
//
#include <hip/hip_runtime.h>
#include <cmath>

#define N_NODES 50000
#define N_EDGES 100000
#define HALF_N  25000
#define DIM     256
#define FFDIM   1024
#define NDEPTH  2
#define MAXDEG  64

typedef __bf16 bf16;
typedef bf16 bf16x8 __attribute__((ext_vector_type(8)));
typedef bf16 bf16x4 __attribute__((ext_vector_type(4)));
typedef float f32x4 __attribute__((ext_vector_type(4)));

__device__ __forceinline__ float wave_sum(float v) {
  v += __shfl_xor(v, 1);
  v += __shfl_xor(v, 2);
  v += __shfl_xor(v, 4);
  v += __shfl_xor(v, 8);
  v += __shfl_xor(v, 16);
  v += __shfl_xor(v, 32);
  return v;
}

// ---------------- LayerNorm: fp32 in -> bf16 out (wave per row) ----------------
__global__ void ln_kernel(const float* __restrict__ in, const float* __restrict__ g,
                          const float* __restrict__ b, bf16* __restrict__ out, int rows) {
  int row = blockIdx.x * 4 + (threadIdx.x >> 6);
  if (row >= rows) return;
  int lane = threadIdx.x & 63;
  float4 x = reinterpret_cast<const float4*>(in + (size_t)row * DIM)[lane];
  float mu = wave_sum(x.x + x.y + x.z + x.w) * (1.0f / DIM);
  float d0 = x.x - mu, d1 = x.y - mu, d2 = x.z - mu, d3 = x.w - mu;
  float var = wave_sum(d0*d0 + d1*d1 + d2*d2 + d3*d3) * (1.0f / DIM);
  float r = rsqrtf(var + 1e-5f);
  float4 gv = reinterpret_cast<const float4*>(g)[lane];
  float4 bv = reinterpret_cast<const float4*>(b)[lane];
  bf16x4 o;
  o[0] = (bf16)(d0 * r * gv.x + bv.x);
  o[1] = (bf16)(d1 * r * gv.y + bv.y);
  o[2] = (bf16)(d2 * r * gv.z + bv.z);
  o[3] = (bf16)(d3 * r * gv.w + bv.w);
  reinterpret_cast<bf16x4*>(out + (size_t)row * DIM)[lane] = o;
}

// ---------------- bf16 MFMA GEMM: C[M,N] = A[M,K](bf16) @ Wt[N,K]^T (+bias) ----
// 128x128 tile, BK=32, 256 threads (4 waves as 2x2 of 64x64).
// LDS chunk layout: index = k8*128 + row  (16B chunks of 8 bf16) -> conflict-free.
// EPI: 1 = exact GELU. OBF: 1 = bf16 output.
template<int EPI, int OBF>
__global__ __launch_bounds__(256) void gemm_mfma(
    const bf16* __restrict__ A, const bf16* __restrict__ Wt,
    const float* __restrict__ bias, void* __restrict__ Cout,
    int M, int K, int N) {
  __shared__ bf16x8 As[512];
  __shared__ bf16x8 Bs[512];
  int tid = threadIdx.x;
  int lane = tid & 63, wave = tid >> 6;
  int wr = wave >> 1, wc = wave & 1;
  int row0 = blockIdx.y * 128, col0 = blockIdx.x * 128;
  int lm = lane & 15, kb = lane >> 4;
  f32x4 acc[4][4] = {};
  int rowa = tid & 127;
  int rga = row0 + rowa; if (rga >= M) rga = M - 1;
  int k8a = tid >> 7;                       // 0 or 1
  const bf16* pA0 = A + (size_t)rga * K + k8a * 8;
  const bf16* pB0 = Wt + (size_t)(col0 + rowa) * K + k8a * 8;
  for (int k0 = 0; k0 < K; k0 += 32) {
    __syncthreads();
    As[tid]       = *reinterpret_cast<const bf16x8*>(pA0 + k0);
    As[tid + 256] = *reinterpret_cast<const bf16x8*>(pA0 + k0 + 16);
    Bs[tid]       = *reinterpret_cast<const bf16x8*>(pB0 + k0);
    Bs[tid + 256] = *reinterpret_cast<const bf16x8*>(pB0 + k0 + 16);
    __syncthreads();
    bf16x8 af[4], bfb[4];
#pragma unroll
    for (int mi = 0; mi < 4; ++mi) af[mi] = As[kb * 128 + wr * 64 + mi * 16 + lm];
#pragma unroll
    for (int ni = 0; ni < 4; ++ni) bfb[ni] = Bs[kb * 128 + wc * 64 + ni * 16 + lm];
#pragma unroll
    for (int mi = 0; mi < 4; ++mi)
#pragma unroll
      for (int ni = 0; ni < 4; ++ni)
        acc[mi][ni] = __builtin_amdgcn_mfma_f32_16x16x32_bf16(af[mi], bfb[ni], acc[mi][ni], 0, 0, 0);
  }
#pragma unroll
  for (int ni = 0; ni < 4; ++ni) {
    int col = col0 + wc * 64 + ni * 16 + lm;
    float bv = bias ? bias[col] : 0.0f;
#pragma unroll
    for (int mi = 0; mi < 4; ++mi) {
#pragma unroll
      for (int r = 0; r < 4; ++r) {
        int row = row0 + wr * 64 + mi * 16 + kb * 4 + r;
        if (row < M) {
          float v = acc[mi][ni][r] + bv;
          if (EPI == 1) v = 0.5f * v * (1.0f + erff(v * 0.70710678118654752f));
          if (OBF) ((bf16*)Cout)[(size_t)row * N + col] = (bf16)v;
          else     ((float*)Cout)[(size_t)row * N + col] = v;
        }
      }
    }
  }
}

// ---------------- fold eA into k and v (qkv layout [HALF][768]) ----------------
__global__ void fold_ea(float* __restrict__ qkv, const float* __restrict__ eAB) {
  size_t idx = (size_t)blockIdx.x * 256 + threadIdx.x;
  if (idx >= (size_t)HALF_N * 64) return;
  size_t row = idx >> 6; int c = idx & 63;
  float4 a = reinterpret_cast<const float4*>(eAB)[row * 128 + c];
  float4* kp = reinterpret_cast<float4*>(qkv) + row * 192 + 64 + c;
  float4 k = kp[0];
  k.x += a.x; k.y += a.y; k.z += a.z; k.w += a.w;
  kp[0] = k;
  float4 v = kp[64];
  v.x += a.x; v.y += a.y; v.z += a.z; v.w += a.w;
  kp[64] = v;
}

// ---------------- ELL build ----------------
__global__ void ell_build(const int* __restrict__ ei, int* __restrict__ deg,
                          int* __restrict__ ell) {
  int e = blockIdx.x * 256 + threadIdx.x;
  if (e >= N_EDGES) return;
  int s = ei[e], d = ei[N_EDGES + e];
  int pos = atomicAdd(&deg[d], 1);
  if (pos < MAXDEG) ell[d * MAXDEG + pos] = s;
}

// ---------------- attention gather (wave per dst node, online softmax) --------
__global__ void attn_gather(const int* __restrict__ deg, const int* __restrict__ ell,
                            const float* __restrict__ qkv, const float* __restrict__ eAB,
                            bf16* __restrict__ agg) {
  int d = blockIdx.x * 4 + (threadIdx.x >> 6);
  if (d >= HALF_N) return;
  int lane = threadIdx.x & 63;
  int cnt = deg[d]; if (cnt > MAXDEG) cnt = MAXDEG;
  float4 qv = reinterpret_cast<const float4*>(qkv + (size_t)d * 768)[lane];
  float m = -INFINITY, den = 0.0f;
  float a0 = 0.0f, a1 = 0.0f, a2 = 0.0f, a3 = 0.0f;
  for (int i = 0; i < cnt; ++i) {
    int s = ell[d * MAXDEG + i];
    float4 kv4 = reinterpret_cast<const float4*>(qkv + (size_t)s * 768 + 256)[lane];
    float4 vv  = reinterpret_cast<const float4*>(qkv + (size_t)s * 768 + 512)[lane];
    float p = qv.x * kv4.x + qv.y * kv4.y + qv.z * kv4.z + qv.w * kv4.w;
    p += __shfl_xor(p, 1); p += __shfl_xor(p, 2);
    p += __shfl_xor(p, 4); p += __shfl_xor(p, 8);
    float sim = p * 0.125f;                          // DH^-0.5
    float nm = fmaxf(m, sim);
    float sc = expf(m - nm);                         // first iter: exp(-inf)=0
    float w  = expf(sim - nm);
    den = den * sc + w;
    a0 = a0 * sc + w * vv.x;
    a1 = a1 * sc + w * vv.y;
    a2 = a2 * sc + w * vv.z;
    a3 = a3 * sc + w * vv.w;
    m = nm;
  }
  bf16x4 o;
  if (cnt > 0) {
    float inv = 1.0f / den;
    float4 eb = reinterpret_cast<const float4*>(eAB + (size_t)d * 512 + 256)[lane];
    o[0] = (bf16)(a0 * inv + eb.x);
    o[1] = (bf16)(a1 * inv + eb.y);
    o[2] = (bf16)(a2 * inv + eb.z);
    o[3] = (bf16)(a3 * inv + eb.w);
  } else {
    o[0] = (bf16)0.0f; o[1] = (bf16)0.0f; o[2] = (bf16)0.0f; o[3] = (bf16)0.0f;
  }
  reinterpret_cast<bf16x4*>(agg + (size_t)d * DIM)[lane] = o;
}

// ---------------- gated residual (wave per row, fp32) ----------------
__global__ void gated_res(const float* __restrict__ xin, const float* __restrict__ fb,
                          float* __restrict__ nodes, const float* __restrict__ w,
                          int rows, int xvr) {
  int r = blockIdx.x * 4 + (threadIdx.x >> 6);
  if (r >= rows) return;
  int lane = threadIdx.x & 63;
  float4 xv = (r < xvr) ? reinterpret_cast<const float4*>(xin + (size_t)r * DIM)[lane]
                        : reinterpret_cast<const float4*>(fb)[lane];
  float4 rv = reinterpret_cast<const float4*>(nodes + (size_t)r * DIM)[lane];
  float4 w0 = reinterpret_cast<const float4*>(w)[lane];
  float4 w1 = reinterpret_cast<const float4*>(w + 256)[lane];
  float4 w2 = reinterpret_cast<const float4*>(w + 512)[lane];
  float p = xv.x * (w0.x + w2.x) + rv.x * (w1.x - w2.x)
          + xv.y * (w0.y + w2.y) + rv.y * (w1.y - w2.y)
          + xv.z * (w0.z + w2.z) + rv.z * (w1.z - w2.z)
          + xv.w * (w0.w + w2.w) + rv.w * (w1.w - w2.w);
  p = wave_sum(p);
  float gate = 1.0f / (1.0f + expf(-p));
  float4 o;
  o.x = xv.x * gate + rv.x * (1.0f - gate);
  o.y = xv.y * gate + rv.y * (1.0f - gate);
  o.z = xv.z * gate + rv.z * (1.0f - gate);
  o.w = xv.w * gate + rv.w * (1.0f - gate);
  reinterpret_cast<float4*>(nodes + (size_t)r * DIM)[lane] = o;
}

// ---------------- final projection + output scatter ----------------
__global__ void out_kernel(const float* __restrict__ nodes, const float* __restrict__ Wout,
                           const float* __restrict__ bout, float* __restrict__ out) {
  int r = blockIdx.x * 4 + (threadIdx.x >> 6);
  if (r >= N_NODES) return;
  int lane = threadIdx.x & 63;
  float4 nv = reinterpret_cast<const float4*>(nodes + (size_t)r * DIM)[lane];
  float4 wv = reinterpret_cast<const float4*>(Wout)[lane];
  float p = nv.x * wv.x + nv.y * wv.y + nv.z * wv.z + nv.w * wv.w;
  p = wave_sum(p);
  if (lane == 0) {
    float z = p + bout[0];
    if (r < HALF_N) {
      out[HALF_N + r] = z;
    } else {
      int j = r - HALF_N;
      out[j] = z;
      out[2 * HALF_N + j] = z;
    }
  }
}

// ---------------- weight prep: transpose + bf16 convert ----------------
// per-layer layout (bf16 elems): qkvT[768][256] @0, eABT[512][256] @196608,
// WoT[256][256] @327680, W1T[1024][256] @393216, W2T[256][1024] @655360. total 917504.
__global__ void prep_w(const float* __restrict__ Wq, const float* __restrict__ Wkv,
                       const float* __restrict__ We, const float* __restrict__ Wo,
                       const float* __restrict__ W1, const float* __restrict__ W2,
                       bf16* __restrict__ wt) {
  int idx = blockIdx.x * 256 + threadIdx.x;
  if (idx >= 2 * 917504) return;
  int l = idx / 917504, r = idx % 917504;
  float v;
  if (r < 196608) {
    int n = r >> 8, k = r & 255;
    v = (n < 256) ? Wq[l * 65536 + k * 256 + n] : Wkv[l * 131072 + k * 512 + (n - 256)];
  } else if (r < 327680) {
    int rr = r - 196608; int n = rr >> 8, k = rr & 255;
    v = (n < 256) ? We[l * 131072 + k * 256 + n] : We[l * 131072 + (k + 256) * 256 + (n - 256)];
  } else if (r < 393216) {
    int rr = r - 327680; int n = rr >> 8, k = rr & 255;
    v = Wo[l * 65536 + k * 256 + n];
  } else if (r < 655360) {
    int rr = r - 393216; int n = rr >> 8, k = rr & 255;
    v = W1[l * 262144 + k * 1024 + n];
  } else {
    int rr = r - 655360; int n = rr >> 10, k = rr & 1023;
    v = W2[l * 262144 + k * 256 + n];
  }
  wt[idx] = (bf16)v;
}

// biasbuf: [2*768 qkv | 2*512 eAB]
__global__ void prep_bias(const float* __restrict__ bq, const float* __restrict__ bkv,
                          const float* __restrict__ be, float* __restrict__ biasbuf) {
  int i = blockIdx.x * 256 + threadIdx.x;
  if (i < 2 * 768) {
    int l = i / 768, c = i % 768;
    biasbuf[i] = (c < 256) ? bq[l * 256 + c] : bkv[l * 512 + (c - 256)];
  } else if (i < 2 * 768 + 2 * 512) {
    int j = i - 1536; int l = j / 512, c = j % 512;
    biasbuf[i] = (c < 256) ? 0.0f : be[l * 256 + (c - 256)];
  }
}

__global__ void prep_x(const float* __restrict__ x, bf16* __restrict__ xb) {
  int i = blockIdx.x * 256 + threadIdx.x;
  if (i >= HALF_N * 64) return;
  float4 v = reinterpret_cast<const float4*>(x)[i];
  bf16x4 o;
  o[0] = (bf16)v.x; o[1] = (bf16)v.y; o[2] = (bf16)v.z; o[3] = (bf16)v.w;
  reinterpret_cast<bf16x4*>(xb)[i] = o;
}

extern "C" void kernel_launch(void* const* d_in, const int* in_sizes, int n_in,
                              void* d_out, int out_size, void* d_ws, size_t ws_size,
                              hipStream_t stream) {
  const float* x     = (const float*)d_in[0];
  const int*   ei    = (const int*)d_in[1];
  const float* ln1_g = (const float*)d_in[2];
  const float* ln1_b = (const float*)d_in[3];
  const float* Wq    = (const float*)d_in[4];
  const float* bq    = (const float*)d_in[5];
  const float* Wkv   = (const float*)d_in[6];
  const float* bkv   = (const float*)d_in[7];
  const float* We    = (const float*)d_in[8];
  const float* be    = (const float*)d_in[9];
  const float* Wo    = (const float*)d_in[10];
  const float* bo    = (const float*)d_in[11];
  const float* g_attn= (const float*)d_in[12];
  const float* ln2_g = (const float*)d_in[13];
  const float* ln2_b = (const float*)d_in[14];
  const float* W1    = (const float*)d_in[15];
  const float* b1    = (const float*)d_in[16];
  const float* W2    = (const float*)d_in[17];
  const float* b2    = (const float*)d_in[18];
  const float* g_ff  = (const float*)d_in[19];
  const float* Wout  = (const float*)d_in[20];
  const float* bout  = (const float*)d_in[21];
  float* out = (float*)d_out;

  char* base = (char*)d_ws;
  float* nodes   = (float*)base;  base += (size_t)N_NODES * DIM * 4;      // 51.2 MB
  bf16*  xn_bf   = (bf16*)base;   base += (size_t)N_NODES * DIM * 2;      // 25.6 MB
  bf16*  x_bf    = (bf16*)base;   base += (size_t)HALF_N * DIM * 2;       // 12.8 MB
  bf16*  agg_bf  = (bf16*)base;   base += (size_t)HALF_N * DIM * 2;       // 12.8 MB
  bf16*  wt      = (bf16*)base;   base += (size_t)2 * 917504 * 2;         // 3.67 MB
  float* biasbuf = (float*)base;  base += 2560 * 4;                       // 10 KB
  int*   deg     = (int*)base;    base += HALF_N * 4;                     // 0.1 MB
  int*   ell     = (int*)base;    base += (size_t)HALF_N * MAXDEG * 4;    // 6.4 MB
  float* qkv     = (float*)base;  base += (size_t)HALF_N * 768 * 4;       // 76.8 MB (h aliases)
  float* eAB     = (float*)base;  base += (size_t)HALF_N * 512 * 4;       // 51.2 MB (attn_out/ffout alias)
  bf16*  hbuf    = (bf16*)qkv;
  float* attn_out = eAB;
  float* ffout    = eAB;

  // one-time prep
  hipMemcpyAsync(nodes, x, (size_t)N_NODES * DIM * sizeof(float),
                 hipMemcpyDeviceToDevice, stream);
  prep_w<<<(2 * 917504 + 255) / 256, 256, 0, stream>>>(Wq, Wkv, We, Wo, W1, W2, wt);
  prep_bias<<<10, 256, 0, stream>>>(bq, bkv, be, biasbuf);
  prep_x<<<(HALF_N * 64 + 255) / 256, 256, 0, stream>>>(x, x_bf);
  hipMemsetAsync(deg, 0, HALF_N * sizeof(int), stream);
  ell_build<<<(N_EDGES + 255) / 256, 256, 0, stream>>>(ei, deg, ell);

  const int MB = (HALF_N + 127) / 128;   // 196

  for (int l = 0; l < NDEPTH; ++l) {
    const bf16* wl = wt + (size_t)l * 917504;
    // LN1 over first HALF rows only
    ln_kernel<<<(HALF_N + 3) / 4, 256, 0, stream>>>(nodes, ln1_g + l * DIM, ln1_b + l * DIM, xn_bf, HALF_N);
    // qkv = xn @ [Wq|Wkv] + [bq|bkv]
    gemm_mfma<0,0><<<dim3(6, MB), 256, 0, stream>>>(xn_bf, wl, biasbuf + l * 768, qkv, HALF_N, 256, 768);
    // eAB = x @ [We_top|We_bot] + [0|be]
    gemm_mfma<0,0><<<dim3(4, MB), 256, 0, stream>>>(x_bf, wl + 196608, biasbuf + 1536 + l * 512, eAB, HALF_N, 256, 512);
    // k += eA ; v += eA
    fold_ea<<<(HALF_N * 64 + 255) / 256, 256, 0, stream>>>(qkv, eAB);
    // gather attention -> agg (bf16), + eB for non-empty segments
    attn_gather<<<(HALF_N + 3) / 4, 256, 0, stream>>>(deg, ell, qkv, eAB, agg_bf);
    // attn_out = agg @ Wo + bo
    gemm_mfma<0,0><<<dim3(2, MB), 256, 0, stream>>>(agg_bf, wl + 327680, bo + l * DIM, attn_out, HALF_N, 256, 256);
    // gated residual 1 (rows >= HALF use bo)
    gated_res<<<(N_NODES + 3) / 4, 256, 0, stream>>>(attn_out, bo + l * DIM, nodes, g_attn + l * 768, N_NODES, HALF_N);
    // LN2 over all rows
    ln_kernel<<<(N_NODES + 3) / 4, 256, 0, stream>>>(nodes, ln2_g + l * DIM, ln2_b + l * DIM, xn_bf, N_NODES);
    // FF in two 25000-row chunks
    for (int c = 0; c < 2; ++c) {
      const bf16* xin = xn_bf + (size_t)c * HALF_N * DIM;
      gemm_mfma<1,1><<<dim3(8, MB), 256, 0, stream>>>(xin, wl + 393216, b1 + l * FFDIM, hbuf, HALF_N, 256, 1024);
      gemm_mfma<0,0><<<dim3(2, MB), 256, 0, stream>>>(hbuf, wl + 655360, b2 + l * DIM, ffout, HALF_N, 1024, 256);
      gated_res<<<(HALF_N + 3) / 4, 256, 0, stream>>>(ffout, nullptr, nodes + (size_t)c * HALF_N * DIM, g_ff + l * 768, HALF_N, HALF_N);
    }
  }

  out_kernel<<<(N_NODES + 3) / 4, 256, 0, stream>>>(nodes, Wout, bout, out);
}

// Round 3
// 793.319 us; speedup vs baseline: 6.0102x; 1.3999x over previous
//
#include <hip/hip_runtime.h>
#include <cmath>

#define N_NODES 50000
#define N_EDGES 100000
#define HALF_N  25000
#define DIM     256
#define NDEPTH  2
#define MAXDEG  64

// per-layer weight-buffer offsets (bf16 elements)
#define WT_QKVE 0
#define WT_WO   524288
#define WT_W1   589824
#define WT_W2   851968
#define WT_LAYER 1114112

typedef __bf16 bf16;
typedef bf16 bf16x8 __attribute__((ext_vector_type(8)));
typedef bf16 bf16x4 __attribute__((ext_vector_type(4)));
typedef float f32x4 __attribute__((ext_vector_type(4)));

__device__ __forceinline__ float wave_sum(float v) {
  v += __shfl_xor(v, 1);
  v += __shfl_xor(v, 2);
  v += __shfl_xor(v, 4);
  v += __shfl_xor(v, 8);
  v += __shfl_xor(v, 16);
  v += __shfl_xor(v, 32);
  return v;
}

// ---------------- layer-0 LN1: x -> A2 left half (stride 512) ----------------
__global__ void ln0_kernel(const float* __restrict__ in, const float* __restrict__ g,
                           const float* __restrict__ b, bf16* __restrict__ A2) {
  int row = blockIdx.x * 4 + (threadIdx.x >> 6);
  if (row >= HALF_N) return;
  int lane = threadIdx.x & 63;
  float4 x = reinterpret_cast<const float4*>(in + (size_t)row * DIM)[lane];
  float mu = wave_sum(x.x + x.y + x.z + x.w) * (1.0f / DIM);
  float d0 = x.x - mu, d1 = x.y - mu, d2 = x.z - mu, d3 = x.w - mu;
  float var = wave_sum(d0*d0 + d1*d1 + d2*d2 + d3*d3) * (1.0f / DIM);
  float r = rsqrtf(var + 1e-5f);
  float4 gv = reinterpret_cast<const float4*>(g)[lane];
  float4 bv = reinterpret_cast<const float4*>(b)[lane];
  bf16x4 o;
  o[0] = (bf16)(d0 * r * gv.x + bv.x);
  o[1] = (bf16)(d1 * r * gv.y + bv.y);
  o[2] = (bf16)(d2 * r * gv.z + bv.z);
  o[3] = (bf16)(d3 * r * gv.w + bv.w);
  *reinterpret_cast<bf16x4*>(A2 + (size_t)row * 512 + lane * 4) = o;
}

// ---------------- bf16 MFMA GEMM: C[M,N](bf16) = A[M,K] @ Wt[N,K]^T + bias ----
// 128x128 tile, BK=32, 256 threads. LDS-staged coalesced bf16 epilogue.
// EPI=1: exact GELU.
template<int EPI>
__global__ __launch_bounds__(256) void gemm_mfma(
    const bf16* __restrict__ A, const bf16* __restrict__ Wt,
    const float* __restrict__ bias, bf16* __restrict__ C,
    int M, int K, int N) {
  __shared__ bf16 smem[17408];                 // 34816 B
  bf16x8* As = (bf16x8*)smem;                  // [512] (8 KB)
  bf16x8* Bs = As + 512;                       // [512] (8 KB)
  bf16* Cs = smem;                             // C tile, row stride 136 (aliased)
  int tid = threadIdx.x;
  int lane = tid & 63, wave = tid >> 6;
  int wr = wave >> 1, wc = wave & 1;
  int row0 = blockIdx.y * 128, col0 = blockIdx.x * 128;
  int lm = lane & 15, kb = lane >> 4;
  f32x4 acc[4][4] = {};
  int rowa = tid & 127;
  int rga = row0 + rowa; if (rga >= M) rga = M - 1;
  int k8a = tid >> 7;
  const bf16* pA0 = A + (size_t)rga * K + k8a * 8;
  const bf16* pB0 = Wt + (size_t)(col0 + rowa) * K + k8a * 8;
  for (int k0 = 0; k0 < K; k0 += 32) {
    __syncthreads();
    As[tid]       = *reinterpret_cast<const bf16x8*>(pA0 + k0);
    As[tid + 256] = *reinterpret_cast<const bf16x8*>(pA0 + k0 + 16);
    Bs[tid]       = *reinterpret_cast<const bf16x8*>(pB0 + k0);
    Bs[tid + 256] = *reinterpret_cast<const bf16x8*>(pB0 + k0 + 16);
    __syncthreads();
    bf16x8 af[4], bfb[4];
#pragma unroll
    for (int mi = 0; mi < 4; ++mi) af[mi] = As[kb * 128 + wr * 64 + mi * 16 + lm];
#pragma unroll
    for (int ni = 0; ni < 4; ++ni) bfb[ni] = Bs[kb * 128 + wc * 64 + ni * 16 + lm];
#pragma unroll
    for (int mi = 0; mi < 4; ++mi)
#pragma unroll
      for (int ni = 0; ni < 4; ++ni)
        acc[mi][ni] = __builtin_amdgcn_mfma_f32_16x16x32_bf16(af[mi], bfb[ni], acc[mi][ni], 0, 0, 0);
  }
  __syncthreads();   // all waves done with As/Bs before Cs overwrite
#pragma unroll
  for (int ni = 0; ni < 4; ++ni) {
    int cl = wc * 64 + ni * 16 + lm;
    float bv = bias[col0 + cl];
#pragma unroll
    for (int mi = 0; mi < 4; ++mi) {
#pragma unroll
      for (int r = 0; r < 4; ++r) {
        int rl = wr * 64 + mi * 16 + kb * 4 + r;
        float v = acc[mi][ni][r] + bv;
        if (EPI == 1) v = 0.5f * v * (1.0f + erff(v * 0.70710678118654752f));
        Cs[rl * 136 + cl] = (bf16)v;
      }
    }
  }
  __syncthreads();
  int rbase = tid >> 4, cbase = (tid & 15) * 8;
#pragma unroll
  for (int rr = 0; rr < 8; ++rr) {
    int rl = rr * 16 + rbase;
    int grow = row0 + rl;
    if (grow < M) {
      bf16x8 v = *reinterpret_cast<const bf16x8*>(Cs + rl * 136 + cbase);
      *reinterpret_cast<bf16x8*>(C + (size_t)grow * N + col0 + cbase) = v;
    }
  }
}

// ---------------- ELL build ----------------
__global__ void ell_build(const int* __restrict__ ei, int* __restrict__ deg,
                          int* __restrict__ ell) {
  int e = blockIdx.x * 256 + threadIdx.x;
  if (e >= N_EDGES) return;
  int s = ei[e], d = ei[N_EDGES + e];
  int pos = atomicAdd(&deg[d], 1);
  if (pos < MAXDEG) ell[d * MAXDEG + pos] = s;
}

// ---------------- attention gather (wave per dst, online softmax, bf16) ------
// qkv layout [HALF][1024]: q|k'|v'|eB. agg = softmax-agg(v') + eB (cnt>0).
__global__ void attn_gather(const int* __restrict__ deg, const int* __restrict__ ell,
                            const bf16* __restrict__ qkv, bf16* __restrict__ agg) {
  int d = blockIdx.x * 4 + (threadIdx.x >> 6);
  if (d >= HALF_N) return;
  int lane = threadIdx.x & 63;
  int cnt = deg[d]; if (cnt > MAXDEG) cnt = MAXDEG;
  const bf16* qr = qkv + (size_t)d * 1024;
  bf16x4 qb = *reinterpret_cast<const bf16x4*>(qr + lane * 4);
  float q0 = (float)qb[0], q1 = (float)qb[1], q2 = (float)qb[2], q3 = (float)qb[3];
  float m = -INFINITY, den = 0.0f, a0 = 0.0f, a1 = 0.0f, a2 = 0.0f, a3 = 0.0f;
  for (int i = 0; i < cnt; ++i) {
    int s = ell[d * MAXDEG + i];
    const bf16* kr = qkv + (size_t)s * 1024;
    bf16x4 kb4 = *reinterpret_cast<const bf16x4*>(kr + 256 + lane * 4);
    bf16x4 vb4 = *reinterpret_cast<const bf16x4*>(kr + 512 + lane * 4);
    float p = q0 * (float)kb4[0] + q1 * (float)kb4[1] +
              q2 * (float)kb4[2] + q3 * (float)kb4[3];
    p += __shfl_xor(p, 1); p += __shfl_xor(p, 2);
    p += __shfl_xor(p, 4); p += __shfl_xor(p, 8);
    float sim = p * 0.125f;                       // DH^-0.5
    float nm = fmaxf(m, sim);
    float sc = expf(m - nm);
    float w  = expf(sim - nm);
    den = den * sc + w;
    a0 = a0 * sc + w * (float)vb4[0];
    a1 = a1 * sc + w * (float)vb4[1];
    a2 = a2 * sc + w * (float)vb4[2];
    a3 = a3 * sc + w * (float)vb4[3];
    m = nm;
  }
  bf16x4 o;
  if (cnt > 0) {
    float inv = 1.0f / den;
    bf16x4 eb = *reinterpret_cast<const bf16x4*>(qr + 768 + lane * 4);
    o[0] = (bf16)(a0 * inv + (float)eb[0]);
    o[1] = (bf16)(a1 * inv + (float)eb[1]);
    o[2] = (bf16)(a2 * inv + (float)eb[2]);
    o[3] = (bf16)(a3 * inv + (float)eb[3]);
  } else {
    o[0] = (bf16)0.0f; o[1] = (bf16)0.0f; o[2] = (bf16)0.0f; o[3] = (bf16)0.0f;
  }
  *reinterpret_cast<bf16x4*>(agg + (size_t)d * DIM + lane * 4) = o;
}

// ---------------- fused gated-residual (+LN) (+final out-proj) ----------------
template<int DO_LN, int DO_OUT>
__global__ void gr_ln(const bf16* __restrict__ xin, const float* __restrict__ fb,
                      float* __restrict__ nodes, const float* __restrict__ w,
                      const float* __restrict__ g, const float* __restrict__ b,
                      bf16* __restrict__ xn, int xn_stride, int ln_rows,
                      const float* __restrict__ Wout, const float* __restrict__ bout,
                      float* __restrict__ out, int rows, int xvr, int row_off) {
  int r = blockIdx.x * 4 + (threadIdx.x >> 6);
  if (r >= rows) return;
  int lane = threadIdx.x & 63;
  float x0, x1, x2, x3;
  if (r < xvr) {
    bf16x4 xb = *reinterpret_cast<const bf16x4*>(xin + (size_t)r * DIM + lane * 4);
    x0 = (float)xb[0]; x1 = (float)xb[1]; x2 = (float)xb[2]; x3 = (float)xb[3];
  } else {
    float4 f = reinterpret_cast<const float4*>(fb)[lane];
    x0 = f.x; x1 = f.y; x2 = f.z; x3 = f.w;
  }
  float4 rv = reinterpret_cast<const float4*>(nodes + (size_t)r * DIM)[lane];
  float4 w0 = reinterpret_cast<const float4*>(w)[lane];
  float4 w1 = reinterpret_cast<const float4*>(w + 256)[lane];
  float4 w2 = reinterpret_cast<const float4*>(w + 512)[lane];
  float p = x0 * (w0.x + w2.x) + rv.x * (w1.x - w2.x)
          + x1 * (w0.y + w2.y) + rv.y * (w1.y - w2.y)
          + x2 * (w0.z + w2.z) + rv.z * (w1.z - w2.z)
          + x3 * (w0.w + w2.w) + rv.w * (w1.w - w2.w);
  p = wave_sum(p);
  float gate = 1.0f / (1.0f + expf(-p));
  float n0 = x0 * gate + rv.x * (1.0f - gate);
  float n1 = x1 * gate + rv.y * (1.0f - gate);
  float n2 = x2 * gate + rv.z * (1.0f - gate);
  float n3 = x3 * gate + rv.w * (1.0f - gate);
  if (!DO_OUT) {
    float4 o; o.x = n0; o.y = n1; o.z = n2; o.w = n3;
    reinterpret_cast<float4*>(nodes + (size_t)r * DIM)[lane] = o;
  }
  if (DO_LN) {
    if (r < ln_rows) {
      float mu = wave_sum(n0 + n1 + n2 + n3) * (1.0f / DIM);
      float d0 = n0 - mu, d1 = n1 - mu, d2 = n2 - mu, d3 = n3 - mu;
      float var = wave_sum(d0*d0 + d1*d1 + d2*d2 + d3*d3) * (1.0f / DIM);
      float rs = rsqrtf(var + 1e-5f);
      float4 gv = reinterpret_cast<const float4*>(g)[lane];
      float4 bv = reinterpret_cast<const float4*>(b)[lane];
      bf16x4 o;
      o[0] = (bf16)(d0 * rs * gv.x + bv.x);
      o[1] = (bf16)(d1 * rs * gv.y + bv.y);
      o[2] = (bf16)(d2 * rs * gv.z + bv.z);
      o[3] = (bf16)(d3 * rs * gv.w + bv.w);
      *reinterpret_cast<bf16x4*>(xn + (size_t)r * xn_stride + lane * 4) = o;
    }
  }
  if (DO_OUT) {
    float4 wv = reinterpret_cast<const float4*>(Wout)[lane];
    float z = n0 * wv.x + n1 * wv.y + n2 * wv.z + n3 * wv.w;
    z = wave_sum(z);
    if (lane == 0) {
      z += bout[0];
      int gr = row_off + r;
      if (gr < HALF_N) {
        out[HALF_N + gr] = z;
      } else {
        int j = gr - HALF_N;
        out[j] = z;
        out[2 * HALF_N + j] = z;
      }
    }
  }
}

// ---------------- weight prep: combined-transposed bf16 ----------------
__global__ void prep_w(const float* __restrict__ Wq, const float* __restrict__ Wkv,
                       const float* __restrict__ We, const float* __restrict__ Wo,
                       const float* __restrict__ W1, const float* __restrict__ W2,
                       bf16* __restrict__ wt) {
  int idx = blockIdx.x * 256 + threadIdx.x;
  if (idx >= 2 * WT_LAYER) return;
  int l = idx / WT_LAYER, r = idx % WT_LAYER;
  float v;
  if (r < 524288) {                       // qkveT [1024 n][512 k]
    int n = r >> 9, k = r & 511;
    if (n < 256) {
      v = (k < 256) ? Wq[l * 65536 + k * 256 + n] : 0.0f;
    } else if (n < 512) {
      int c = n - 256;
      v = (k < 256) ? Wkv[l * 131072 + k * 512 + c]
                    : We[l * 131072 + (k - 256) * 256 + c];
    } else if (n < 768) {
      int c = n - 512;
      v = (k < 256) ? Wkv[l * 131072 + k * 512 + 256 + c]
                    : We[l * 131072 + (k - 256) * 256 + c];
    } else {
      int c = n - 768;
      v = (k < 256) ? 0.0f : We[l * 131072 + (k - 256 + 256) * 256 + c];
    }
  } else if (r < 589824) {                // WoT [256][256]
    int rr = r - 524288, n = rr >> 8, k = rr & 255;
    v = Wo[l * 65536 + k * 256 + n];
  } else if (r < 851968) {                // W1T [1024][256]
    int rr = r - 589824, n = rr >> 8, k = rr & 255;
    v = W1[l * 262144 + k * 1024 + n];
  } else {                                // W2T [256][1024]
    int rr = r - 851968, n = rr >> 10, k = rr & 1023;
    v = W2[l * 262144 + k * 256 + n];
  }
  wt[idx] = (bf16)v;
}

// qkve bias: [2][1024] = [bq | bk | bv | be]
__global__ void prep_bias(const float* __restrict__ bq, const float* __restrict__ bkv,
                          const float* __restrict__ be, float* __restrict__ biasq) {
  int i = blockIdx.x * 256 + threadIdx.x;
  if (i >= 2048) return;
  int l = i >> 10, n = i & 1023;
  float v;
  if (n < 256) v = bq[l * 256 + n];
  else if (n < 512) v = bkv[l * 512 + (n - 256)];
  else if (n < 768) v = bkv[l * 512 + 256 + (n - 512)];
  else v = be[l * 256 + (n - 768)];
  biasq[i] = v;
}

// x (fp32) -> A2 right half (bf16, stride 512)
__global__ void prep_x(const float* __restrict__ x, bf16* __restrict__ A2) {
  int i = blockIdx.x * 256 + threadIdx.x;
  if (i >= HALF_N * 64) return;
  int row = i >> 6, c = i & 63;
  float4 v = reinterpret_cast<const float4*>(x)[i];
  bf16x4 o;
  o[0] = (bf16)v.x; o[1] = (bf16)v.y; o[2] = (bf16)v.z; o[3] = (bf16)v.w;
  *reinterpret_cast<bf16x4*>(A2 + (size_t)row * 512 + 256 + c * 4) = o;
}

extern "C" void kernel_launch(void* const* d_in, const int* in_sizes, int n_in,
                              void* d_out, int out_size, void* d_ws, size_t ws_size,
                              hipStream_t stream) {
  const float* x     = (const float*)d_in[0];
  const int*   ei    = (const int*)d_in[1];
  const float* ln1_g = (const float*)d_in[2];
  const float* ln1_b = (const float*)d_in[3];
  const float* Wq    = (const float*)d_in[4];
  const float* bq    = (const float*)d_in[5];
  const float* Wkv   = (const float*)d_in[6];
  const float* bkv   = (const float*)d_in[7];
  const float* We    = (const float*)d_in[8];
  const float* be    = (const float*)d_in[9];
  const float* Wo    = (const float*)d_in[10];
  const float* bo    = (const float*)d_in[11];
  const float* g_attn= (const float*)d_in[12];
  const float* ln2_g = (const float*)d_in[13];
  const float* ln2_b = (const float*)d_in[14];
  const float* W1    = (const float*)d_in[15];
  const float* b1    = (const float*)d_in[16];
  const float* W2    = (const float*)d_in[17];
  const float* b2    = (const float*)d_in[18];
  const float* g_ff  = (const float*)d_in[19];
  const float* Wout  = (const float*)d_in[20];
  const float* bout  = (const float*)d_in[21];
  float* out = (float*)d_out;

  char* base = (char*)d_ws;
  float* nodes   = (float*)base;  base += (size_t)N_NODES * DIM * 4;      // 51.2 MB
  bf16*  A2      = (bf16*)base;   base += (size_t)HALF_N * 512 * 2;       // 25.6 MB
  bf16*  xn_bf   = (bf16*)base;   base += (size_t)N_NODES * DIM * 2;      // 25.6 MB
  bf16*  qkv     = (bf16*)base;   base += (size_t)HALF_N * 1024 * 2;      // 51.2 MB
  bf16*  agg     = (bf16*)base;   base += (size_t)HALF_N * DIM * 2;       // 12.8 MB
  bf16*  attn_o  = (bf16*)base;   base += (size_t)HALF_N * DIM * 2;       // 12.8 MB
  bf16*  hbuf    = (bf16*)base;   base += (size_t)HALF_N * 1024 * 2;      // 51.2 MB
  bf16*  ffout   = (bf16*)base;   base += (size_t)HALF_N * DIM * 2;       // 12.8 MB
  bf16*  wt      = (bf16*)base;   base += (size_t)2 * WT_LAYER * 2;       // 4.5 MB
  float* biasq   = (float*)base;  base += 2048 * 4;
  int*   deg     = (int*)base;    base += HALF_N * 4;
  int*   ell     = (int*)base;    base += (size_t)HALF_N * MAXDEG * 4;    // 6.4 MB

  // one-time prep
  hipMemcpyAsync(nodes, x, (size_t)N_NODES * DIM * sizeof(float),
                 hipMemcpyDeviceToDevice, stream);
  prep_w<<<(2 * WT_LAYER + 255) / 256, 256, 0, stream>>>(Wq, Wkv, We, Wo, W1, W2, wt);
  prep_bias<<<8, 256, 0, stream>>>(bq, bkv, be, biasq);
  prep_x<<<(HALF_N * 64 + 255) / 256, 256, 0, stream>>>(x, A2);
  hipMemsetAsync(deg, 0, HALF_N * sizeof(int), stream);
  ell_build<<<(N_EDGES + 255) / 256, 256, 0, stream>>>(ei, deg, ell);

  const int MBH = (HALF_N + 127) / 128;   // 196

  for (int l = 0; l < NDEPTH; ++l) {
    const bf16* wl = wt + (size_t)l * WT_LAYER;
    if (l == 0)
      ln0_kernel<<<(HALF_N + 3) / 4, 256, 0, stream>>>(x, ln1_g, ln1_b, A2);
    // qkv|eB = [xn|x] @ qkveT + bias
    gemm_mfma<0><<<dim3(8, MBH), 256, 0, stream>>>(A2, wl + WT_QKVE, biasq + l * 1024, qkv, HALF_N, 512, 1024);
    // attention gather (+eB)
    attn_gather<<<(HALF_N + 3) / 4, 256, 0, stream>>>(deg, ell, qkv, agg);
    // attn_out = agg @ Wo + bo
    gemm_mfma<0><<<dim3(2, MBH), 256, 0, stream>>>(agg, wl + WT_WO, bo + l * DIM, attn_o, HALF_N, 256, 256);
    // gr1 + ln2 (all rows)
    gr_ln<1,0><<<(N_NODES + 3) / 4, 256, 0, stream>>>(
        attn_o, bo + l * DIM, nodes, g_attn + l * 768,
        ln2_g + l * DIM, ln2_b + l * DIM, xn_bf, DIM, N_NODES,
        nullptr, nullptr, nullptr, N_NODES, HALF_N, 0);
    // FF in two 25000-row chunks (hbuf/ffout reused)
    for (int c = 0; c < 2; ++c) {
      const bf16* xin = xn_bf + (size_t)c * HALF_N * DIM;
      float* nod = nodes + (size_t)c * HALF_N * DIM;
      gemm_mfma<1><<<dim3(8, MBH), 256, 0, stream>>>(xin, wl + WT_W1, b1 + l * 1024, hbuf, HALF_N, 256, 1024);
      gemm_mfma<0><<<dim3(2, MBH), 256, 0, stream>>>(hbuf, wl + WT_W2, b2 + l * DIM, ffout, HALF_N, 1024, 256);
      if (l < NDEPTH - 1) {
        if (c == 0)   // gr2 + ln1(next layer) into A2 left half
          gr_ln<1,0><<<(HALF_N + 3) / 4, 256, 0, stream>>>(
              ffout, nullptr, nod, g_ff + l * 768,
              ln1_g + (l + 1) * DIM, ln1_b + (l + 1) * DIM, A2, 512, HALF_N,
              nullptr, nullptr, nullptr, HALF_N, HALF_N, 0);
        else
          gr_ln<0,0><<<(HALF_N + 3) / 4, 256, 0, stream>>>(
              ffout, nullptr, nod, g_ff + l * 768,
              nullptr, nullptr, nullptr, 0, 0,
              nullptr, nullptr, nullptr, HALF_N, HALF_N, 0);
      } else {        // final layer: gr2 + output projection (no nodes write)
        gr_ln<0,1><<<(HALF_N + 3) / 4, 256, 0, stream>>>(
            ffout, nullptr, nod, g_ff + l * 768,
            nullptr, nullptr, nullptr, 0, 0,
            Wout, bout, out, HALF_N, HALF_N, c * HALF_N);
      }
    }
  }
}

// Round 4
// 553.228 us; speedup vs baseline: 8.6185x; 1.4340x over previous
//
#include <hip/hip_runtime.h>
#include <cmath>

#define N_NODES 50000
#define N_EDGES 100000
#define HALF_N  25000
#define DIM     256
#define NDEPTH  2
#define MAXDEG  64

// per-layer weight-buffer offsets (bf16 elements), chunk-packed layouts
#define WT_QKVE 0          // 8 tiles x [64 k8][128 n] bf16x8
#define WT_WO   524288     // 2 tiles x [32 k8][128 n]
#define WT_W1   589824     // 8 chunks x [32 k8][128 n]
#define WT_W2   851968     // 8 chunks x [16 k8][256 n]
#define WT_LAYER 1114112

typedef __bf16 bf16;
typedef bf16 bf16x8 __attribute__((ext_vector_type(8)));
typedef bf16 bf16x4 __attribute__((ext_vector_type(4)));
typedef float f32x4 __attribute__((ext_vector_type(4)));

__device__ __forceinline__ float wave_sum(float v) {
  v += __shfl_xor(v, 1);
  v += __shfl_xor(v, 2);
  v += __shfl_xor(v, 4);
  v += __shfl_xor(v, 8);
  v += __shfl_xor(v, 16);
  v += __shfl_xor(v, 32);
  return v;
}

// ---------------- layer-0 LN1: x -> A2 left half (stride 512) ----------------
__global__ void ln0_kernel(const float* __restrict__ in, const float* __restrict__ g,
                           const float* __restrict__ b, bf16* __restrict__ A2) {
  int row = blockIdx.x * 4 + (threadIdx.x >> 6);
  if (row >= HALF_N) return;
  int lane = threadIdx.x & 63;
  float4 x = reinterpret_cast<const float4*>(in + (size_t)row * DIM)[lane];
  float mu = wave_sum(x.x + x.y + x.z + x.w) * (1.0f / DIM);
  float d0 = x.x - mu, d1 = x.y - mu, d2 = x.z - mu, d3 = x.w - mu;
  float var = wave_sum(d0*d0 + d1*d1 + d2*d2 + d3*d3) * (1.0f / DIM);
  float r = rsqrtf(var + 1e-5f);
  float4 gv = reinterpret_cast<const float4*>(g)[lane];
  float4 bv = reinterpret_cast<const float4*>(b)[lane];
  bf16x4 o;
  o[0] = (bf16)(d0 * r * gv.x + bv.x);
  o[1] = (bf16)(d1 * r * gv.y + bv.y);
  o[2] = (bf16)(d2 * r * gv.z + bv.z);
  o[3] = (bf16)(d3 * r * gv.w + bv.w);
  *reinterpret_cast<bf16x4*>(A2 + (size_t)row * 512 + lane * 4) = o;
}

// ---------------- N-loop MFMA GEMM: 64-row panel, A staged once -------------
// A [M][KK] bf16; Wp chunk-packed [NJ][KK/8][128] bf16x8; C [M][NJ*128] bf16.
// 256 threads, 4 waves (2x2), per-wave out quadrant 32x64 per column tile.
template<int KK, int NJ>
__global__ __launch_bounds__(256) void gemm_nloop(
    const bf16* __restrict__ A, const bf16* __restrict__ Wp,
    const float* __restrict__ bias, bf16* __restrict__ C, int M) {
  __shared__ bf16x8 As[KK * 8];        // [KK/8 k8][64 row]
  __shared__ bf16x8 Bs[1024];          // [8 k8][128 n] per 64-k step; Cs aliases
  const int tid = threadIdx.x;
  const int lane = tid & 63, wv = tid >> 6;
  const int wr = wv >> 1, wc = wv & 1;
  const int lm = lane & 15, kb = (lane >> 4) & 3;
  const int row0 = blockIdx.x * 64;
#pragma unroll
  for (int i = 0; i < KK / 32; ++i) {
    int idx = tid + i * 256;
    int row = idx & 63, k8 = idx >> 6;
    int rga = row0 + row; if (rga >= M) rga = M - 1;
    As[idx] = *reinterpret_cast<const bf16x8*>(A + (size_t)rga * KK + k8 * 8);
  }
  const bf16x8* Wp8 = reinterpret_cast<const bf16x8*>(Wp);
  for (int jn = 0; jn < NJ; ++jn) {
    f32x4 acc[2][4] = {};
    for (int step = 0; step < KK / 64; ++step) {
      __syncthreads();                 // prior Bs/Cs reads done
#pragma unroll
      for (int i = 0; i < 4; ++i) {
        int idx = tid + i * 256;
        Bs[idx] = Wp8[(size_t)jn * (KK * 16) + step * 1024 + idx];
      }
      __syncthreads();
#pragma unroll
      for (int ks = 0; ks < 2; ++ks) {
        bf16x8 af[2], bf[4];
#pragma unroll
        for (int mi = 0; mi < 2; ++mi)
          af[mi] = As[(step * 8 + ks * 4 + kb) * 64 + wr * 32 + mi * 16 + lm];
#pragma unroll
        for (int ni = 0; ni < 4; ++ni)
          bf[ni] = Bs[(ks * 4 + kb) * 128 + wc * 64 + ni * 16 + lm];
#pragma unroll
        for (int mi = 0; mi < 2; ++mi)
#pragma unroll
          for (int ni = 0; ni < 4; ++ni)
            acc[mi][ni] = __builtin_amdgcn_mfma_f32_16x16x32_bf16(af[mi], bf[ni], acc[mi][ni], 0, 0, 0);
      }
    }
    __syncthreads();                   // Bs reads done before Cs overwrite
    bf16* Cs = (bf16*)Bs;
#pragma unroll
    for (int ni = 0; ni < 4; ++ni) {
      int c = wc * 64 + ni * 16 + lm;
      float bval = bias[jn * 128 + c];
#pragma unroll
      for (int mi = 0; mi < 2; ++mi)
#pragma unroll
        for (int e = 0; e < 4; ++e) {
          int r = wr * 32 + mi * 16 + kb * 4 + e;
          Cs[r * 128 + c] = (bf16)(acc[mi][ni][e] + bval);
        }
    }
    __syncthreads();
    bf16x8* C8 = reinterpret_cast<bf16x8*>(C);
    const bf16x8* Cs8 = (const bf16x8*)Bs;
#pragma unroll
    for (int i = 0; i < 4; ++i) {
      int idx = tid + i * 256;
      int row = idx >> 4, c8 = idx & 15;
      int grow = row0 + row;
      if (grow < M) C8[(size_t)grow * (NJ * 16) + jn * 16 + c8] = Cs8[row * 16 + c8];
    }
  }
}

// ---------------- fused FF: out = gelu(X@W1+b1)@W2+b2, 64-row panel ---------
// 512 threads (8 waves, 2x4). h chunks 64x128 through LDS; out acc in regs.
__global__ __launch_bounds__(512) void ff_fused(
    const bf16* __restrict__ A, const bf16* __restrict__ W1p,
    const float* __restrict__ b1, const bf16* __restrict__ W2p,
    const float* __restrict__ b2, bf16* __restrict__ C, int M) {
  __shared__ bf16x8 Xs[2048];          // [32 k8][64 row]  32 KB
  __shared__ bf16x8 Bs[2048];          // W chunk half     32 KB (Cs aliases)
  __shared__ bf16x8 Hs[1024];          // [16 k8][64 row]  16 KB
  const int tid = threadIdx.x;
  const int lane = tid & 63, wv = tid >> 6;
  const int wr = wv >> 2, wc = wv & 3;
  const int lm = lane & 15, kb = (lane >> 4) & 3;
  const int row0 = blockIdx.x * 64;
#pragma unroll
  for (int i = 0; i < 4; ++i) {
    int idx = tid + i * 512;
    int row = idx & 63, k8 = idx >> 6;
    int rga = row0 + row; if (rga >= M) rga = M - 1;
    Xs[idx] = *reinterpret_cast<const bf16x8*>(A + (size_t)rga * 256 + k8 * 8);
  }
  const bf16x8* W1p8 = (const bf16x8*)W1p;
  const bf16x8* W2p8 = (const bf16x8*)W2p;
  f32x4 acc[2][4] = {};
  bf16* hsb = (bf16*)Hs;
  for (int j = 0; j < 8; ++j) {
    f32x4 acc1[2][2] = {};
#pragma unroll
    for (int half = 0; half < 2; ++half) {
      __syncthreads();                 // prior Bs/Hs reads done
#pragma unroll
      for (int i = 0; i < 4; ++i) {
        int idx = tid + i * 512;
        Bs[idx] = W1p8[j * 4096 + half * 2048 + idx];
      }
      __syncthreads();
#pragma unroll
      for (int ks = 0; ks < 4; ++ks) {
        bf16x8 af[2], bf[2];
#pragma unroll
        for (int mi = 0; mi < 2; ++mi)
          af[mi] = Xs[(half * 16 + ks * 4 + kb) * 64 + wr * 32 + mi * 16 + lm];
#pragma unroll
        for (int ni = 0; ni < 2; ++ni)
          bf[ni] = Bs[(ks * 4 + kb) * 128 + wc * 32 + ni * 16 + lm];
#pragma unroll
        for (int mi = 0; mi < 2; ++mi)
#pragma unroll
          for (int ni = 0; ni < 2; ++ni)
            acc1[mi][ni] = __builtin_amdgcn_mfma_f32_16x16x32_bf16(af[mi], bf[ni], acc1[mi][ni], 0, 0, 0);
      }
    }
    // GELU + pack h chunk into Hs  (h col c = stage-2 k dim)
#pragma unroll
    for (int ni = 0; ni < 2; ++ni) {
      int c = wc * 32 + ni * 16 + lm;
      float bval = b1[j * 128 + c];
#pragma unroll
      for (int mi = 0; mi < 2; ++mi)
#pragma unroll
        for (int e = 0; e < 4; ++e) {
          int r = wr * 32 + mi * 16 + kb * 4 + e;
          float v = acc1[mi][ni][e] + bval;
          v = 0.5f * v * (1.0f + erff(v * 0.70710678118654752f));
          hsb[((c >> 3) * 64 + r) * 8 + (c & 7)] = (bf16)v;
        }
    }
#pragma unroll
    for (int h2 = 0; h2 < 2; ++h2) {
      __syncthreads();                 // Bs reads done + Hs writes visible
#pragma unroll
      for (int i = 0; i < 4; ++i) {
        int idx = tid + i * 512;
        Bs[idx] = W2p8[j * 4096 + h2 * 2048 + idx];
      }
      __syncthreads();
#pragma unroll
      for (int ks = 0; ks < 2; ++ks) {
        bf16x8 af[2], bf[4];
#pragma unroll
        for (int mi = 0; mi < 2; ++mi)
          af[mi] = Hs[(h2 * 8 + ks * 4 + kb) * 64 + wr * 32 + mi * 16 + lm];
#pragma unroll
        for (int ni = 0; ni < 4; ++ni)
          bf[ni] = Bs[(ks * 4 + kb) * 256 + wc * 64 + ni * 16 + lm];
#pragma unroll
        for (int mi = 0; mi < 2; ++mi)
#pragma unroll
          for (int ni = 0; ni < 4; ++ni)
            acc[mi][ni] = __builtin_amdgcn_mfma_f32_16x16x32_bf16(af[mi], bf[ni], acc[mi][ni], 0, 0, 0);
      }
    }
  }
  __syncthreads();
  bf16* Cs = (bf16*)Bs;
#pragma unroll
  for (int ni = 0; ni < 4; ++ni) {
    int c = wc * 64 + ni * 16 + lm;
    float bval = b2[c];
#pragma unroll
    for (int mi = 0; mi < 2; ++mi)
#pragma unroll
      for (int e = 0; e < 4; ++e) {
        int r = wr * 32 + mi * 16 + kb * 4 + e;
        Cs[r * 256 + c] = (bf16)(acc[mi][ni][e] + bval);
      }
  }
  __syncthreads();
  bf16x8* C8 = (bf16x8*)C;
  const bf16x8* Cs8 = (const bf16x8*)Bs;
#pragma unroll
  for (int i = 0; i < 4; ++i) {
    int idx = tid + i * 512;
    int row = idx >> 5, c8 = idx & 31;
    int grow = row0 + row;
    if (grow < M) C8[(size_t)grow * 32 + c8] = Cs8[row * 32 + c8];
  }
}

// ---------------- ELL build ----------------
__global__ void ell_build(const int* __restrict__ ei, int* __restrict__ deg,
                          int* __restrict__ ell) {
  int e = blockIdx.x * 256 + threadIdx.x;
  if (e >= N_EDGES) return;
  int s = ei[e], d = ei[N_EDGES + e];
  int pos = atomicAdd(&deg[d], 1);
  if (pos < MAXDEG) ell[d * MAXDEG + pos] = s;
}

// ---------------- attention gather (wave per dst, online softmax, bf16) ------
__global__ void attn_gather(const int* __restrict__ deg, const int* __restrict__ ell,
                            const bf16* __restrict__ qkv, bf16* __restrict__ agg) {
  int d = blockIdx.x * 4 + (threadIdx.x >> 6);
  if (d >= HALF_N) return;
  int lane = threadIdx.x & 63;
  int cnt = deg[d]; if (cnt > MAXDEG) cnt = MAXDEG;
  const bf16* qr = qkv + (size_t)d * 1024;
  bf16x4 qb = *reinterpret_cast<const bf16x4*>(qr + lane * 4);
  float q0 = (float)qb[0], q1 = (float)qb[1], q2 = (float)qb[2], q3 = (float)qb[3];
  float m = -INFINITY, den = 0.0f, a0 = 0.0f, a1 = 0.0f, a2 = 0.0f, a3 = 0.0f;
  for (int i = 0; i < cnt; ++i) {
    int s = ell[d * MAXDEG + i];
    const bf16* kr = qkv + (size_t)s * 1024;
    bf16x4 kb4 = *reinterpret_cast<const bf16x4*>(kr + 256 + lane * 4);
    bf16x4 vb4 = *reinterpret_cast<const bf16x4*>(kr + 512 + lane * 4);
    float p = q0 * (float)kb4[0] + q1 * (float)kb4[1] +
              q2 * (float)kb4[2] + q3 * (float)kb4[3];
    p += __shfl_xor(p, 1); p += __shfl_xor(p, 2);
    p += __shfl_xor(p, 4); p += __shfl_xor(p, 8);
    float sim = p * 0.125f;
    float nm = fmaxf(m, sim);
    float sc = expf(m - nm);
    float w  = expf(sim - nm);
    den = den * sc + w;
    a0 = a0 * sc + w * (float)vb4[0];
    a1 = a1 * sc + w * (float)vb4[1];
    a2 = a2 * sc + w * (float)vb4[2];
    a3 = a3 * sc + w * (float)vb4[3];
    m = nm;
  }
  bf16x4 o;
  if (cnt > 0) {
    float inv = 1.0f / den;
    bf16x4 eb = *reinterpret_cast<const bf16x4*>(qr + 768 + lane * 4);
    o[0] = (bf16)(a0 * inv + (float)eb[0]);
    o[1] = (bf16)(a1 * inv + (float)eb[1]);
    o[2] = (bf16)(a2 * inv + (float)eb[2]);
    o[3] = (bf16)(a3 * inv + (float)eb[3]);
  } else {
    o[0] = (bf16)0.0f; o[1] = (bf16)0.0f; o[2] = (bf16)0.0f; o[3] = (bf16)0.0f;
  }
  *reinterpret_cast<bf16x4*>(agg + (size_t)d * DIM + lane * 4) = o;
}

// ---------------- fused gated-residual (+LN) (+final out-proj) ----------------
template<int DO_LN, int DO_OUT>
__global__ void gr_ln(const bf16* __restrict__ xin, const float* __restrict__ fb,
                      float* __restrict__ nodes, const float* __restrict__ w,
                      const float* __restrict__ g, const float* __restrict__ b,
                      bf16* __restrict__ xn, int xn_stride, int ln_rows,
                      const float* __restrict__ Wout, const float* __restrict__ bout,
                      float* __restrict__ out, int rows, int xvr, int row_off) {
  int r = blockIdx.x * 4 + (threadIdx.x >> 6);
  if (r >= rows) return;
  int lane = threadIdx.x & 63;
  float x0, x1, x2, x3;
  if (r < xvr) {
    bf16x4 xb = *reinterpret_cast<const bf16x4*>(xin + (size_t)r * DIM + lane * 4);
    x0 = (float)xb[0]; x1 = (float)xb[1]; x2 = (float)xb[2]; x3 = (float)xb[3];
  } else {
    float4 f = reinterpret_cast<const float4*>(fb)[lane];
    x0 = f.x; x1 = f.y; x2 = f.z; x3 = f.w;
  }
  float4 rv = reinterpret_cast<const float4*>(nodes + (size_t)r * DIM)[lane];
  float4 w0 = reinterpret_cast<const float4*>(w)[lane];
  float4 w1 = reinterpret_cast<const float4*>(w + 256)[lane];
  float4 w2 = reinterpret_cast<const float4*>(w + 512)[lane];
  float p = x0 * (w0.x + w2.x) + rv.x * (w1.x - w2.x)
          + x1 * (w0.y + w2.y) + rv.y * (w1.y - w2.y)
          + x2 * (w0.z + w2.z) + rv.z * (w1.z - w2.z)
          + x3 * (w0.w + w2.w) + rv.w * (w1.w - w2.w);
  p = wave_sum(p);
  float gate = 1.0f / (1.0f + expf(-p));
  float n0 = x0 * gate + rv.x * (1.0f - gate);
  float n1 = x1 * gate + rv.y * (1.0f - gate);
  float n2 = x2 * gate + rv.z * (1.0f - gate);
  float n3 = x3 * gate + rv.w * (1.0f - gate);
  if (!DO_OUT) {
    float4 o; o.x = n0; o.y = n1; o.z = n2; o.w = n3;
    reinterpret_cast<float4*>(nodes + (size_t)r * DIM)[lane] = o;
  }
  if (DO_LN) {
    if (r < ln_rows) {
      float mu = wave_sum(n0 + n1 + n2 + n3) * (1.0f / DIM);
      float d0 = n0 - mu, d1 = n1 - mu, d2 = n2 - mu, d3 = n3 - mu;
      float var = wave_sum(d0*d0 + d1*d1 + d2*d2 + d3*d3) * (1.0f / DIM);
      float rs = rsqrtf(var + 1e-5f);
      float4 gv = reinterpret_cast<const float4*>(g)[lane];
      float4 bv = reinterpret_cast<const float4*>(b)[lane];
      bf16x4 o;
      o[0] = (bf16)(d0 * rs * gv.x + bv.x);
      o[1] = (bf16)(d1 * rs * gv.y + bv.y);
      o[2] = (bf16)(d2 * rs * gv.z + bv.z);
      o[3] = (bf16)(d3 * rs * gv.w + bv.w);
      *reinterpret_cast<bf16x4*>(xn + (size_t)r * xn_stride + lane * 4) = o;
    }
  }
  if (DO_OUT) {
    float4 wv = reinterpret_cast<const float4*>(Wout)[lane];
    float z = n0 * wv.x + n1 * wv.y + n2 * wv.z + n3 * wv.w;
    z = wave_sum(z);
    if (lane == 0) {
      z += bout[0];
      int gr = row_off + r;
      if (gr < HALF_N) {
        out[HALF_N + gr] = z;
      } else {
        int j = gr - HALF_N;
        out[j] = z;
        out[2 * HALF_N + j] = z;
      }
    }
  }
}

// ---------------- weight prep: chunk-packed bf16 layouts ----------------
__global__ void prep_w(const float* __restrict__ Wq, const float* __restrict__ Wkv,
                       const float* __restrict__ We, const float* __restrict__ Wo,
                       const float* __restrict__ W1, const float* __restrict__ W2,
                       bf16* __restrict__ wt) {
  int idx = blockIdx.x * 256 + threadIdx.x;
  if (idx >= 2 * WT_LAYER) return;
  int l = idx / WT_LAYER, r = idx % WT_LAYER;
  float v;
  if (r < 524288) {                       // qkve: 8 x [64 k8][128 n][8 e]
    int jn = r >> 16, t = r & 65535;
    int k8 = t >> 10, u = t & 1023, n = u >> 3, e = u & 7;
    int ncol = jn * 128 + n, k = k8 * 8 + e;
    if (ncol < 256) v = (k < 256) ? Wq[l * 65536 + k * 256 + ncol] : 0.0f;
    else if (ncol < 512) { int c = ncol - 256;
      v = (k < 256) ? Wkv[l * 131072 + k * 512 + c] : We[l * 131072 + (k - 256) * 256 + c]; }
    else if (ncol < 768) { int c = ncol - 512;
      v = (k < 256) ? Wkv[l * 131072 + k * 512 + 256 + c] : We[l * 131072 + (k - 256) * 256 + c]; }
    else { int c = ncol - 768;
      v = (k < 256) ? 0.0f : We[l * 131072 + k * 256 + c]; }
  } else if (r < 589824) {                // Wo: 2 x [32 k8][128 n][8 e]
    int rr = r - 524288;
    int jn = rr >> 15, t = rr & 32767;
    int k8 = t >> 10, u = t & 1023, n = u >> 3, e = u & 7;
    v = Wo[l * 65536 + (k8 * 8 + e) * 256 + jn * 128 + n];
  } else if (r < 851968) {                // W1: 8 x [32 k8][128 n][8 e]
    int rr = r - 589824;
    int j = rr >> 15, t = rr & 32767;
    int k8 = t >> 10, u = t & 1023, n = u >> 3, e = u & 7;
    v = W1[l * 262144 + (k8 * 8 + e) * 1024 + j * 128 + n];
  } else {                                // W2: 8 x [16 k8][256 n][8 e]
    int rr = r - 851968;
    int j = rr >> 15, t = rr & 32767;
    int k8 = t >> 11, u = t & 2047, n = u >> 3, e = u & 7;
    v = W2[l * 262144 + (j * 128 + k8 * 8 + e) * 256 + n];
  }
  wt[idx] = (bf16)v;
}

// qkve bias: [2][1024] = [bq | bk | bv | be]
__global__ void prep_bias(const float* __restrict__ bq, const float* __restrict__ bkv,
                          const float* __restrict__ be, float* __restrict__ biasq) {
  int i = blockIdx.x * 256 + threadIdx.x;
  if (i >= 2048) return;
  int l = i >> 10, n = i & 1023;
  float v;
  if (n < 256) v = bq[l * 256 + n];
  else if (n < 512) v = bkv[l * 512 + (n - 256)];
  else if (n < 768) v = bkv[l * 512 + 256 + (n - 512)];
  else v = be[l * 256 + (n - 768)];
  biasq[i] = v;
}

// x (fp32) -> A2 right half (bf16, stride 512)
__global__ void prep_x(const float* __restrict__ x, bf16* __restrict__ A2) {
  int i = blockIdx.x * 256 + threadIdx.x;
  if (i >= HALF_N * 64) return;
  int row = i >> 6, c = i & 63;
  float4 v = reinterpret_cast<const float4*>(x)[i];
  bf16x4 o;
  o[0] = (bf16)v.x; o[1] = (bf16)v.y; o[2] = (bf16)v.z; o[3] = (bf16)v.w;
  *reinterpret_cast<bf16x4*>(A2 + (size_t)row * 512 + 256 + c * 4) = o;
}

extern "C" void kernel_launch(void* const* d_in, const int* in_sizes, int n_in,
                              void* d_out, int out_size, void* d_ws, size_t ws_size,
                              hipStream_t stream) {
  const float* x     = (const float*)d_in[0];
  const int*   ei    = (const int*)d_in[1];
  const float* ln1_g = (const float*)d_in[2];
  const float* ln1_b = (const float*)d_in[3];
  const float* Wq    = (const float*)d_in[4];
  const float* bq    = (const float*)d_in[5];
  const float* Wkv   = (const float*)d_in[6];
  const float* bkv   = (const float*)d_in[7];
  const float* We    = (const float*)d_in[8];
  const float* be    = (const float*)d_in[9];
  const float* Wo    = (const float*)d_in[10];
  const float* bo    = (const float*)d_in[11];
  const float* g_attn= (const float*)d_in[12];
  const float* ln2_g = (const float*)d_in[13];
  const float* ln2_b = (const float*)d_in[14];
  const float* W1    = (const float*)d_in[15];
  const float* b1    = (const float*)d_in[16];
  const float* W2    = (const float*)d_in[17];
  const float* b2    = (const float*)d_in[18];
  const float* g_ff  = (const float*)d_in[19];
  const float* Wout  = (const float*)d_in[20];
  const float* bout  = (const float*)d_in[21];
  float* out = (float*)d_out;

  char* base = (char*)d_ws;
  float* nodes   = (float*)base;  base += (size_t)N_NODES * DIM * 4;      // 51.2 MB
  bf16*  A2      = (bf16*)base;   base += (size_t)HALF_N * 512 * 2;       // 25.6 MB
  bf16*  xn_bf   = (bf16*)base;   base += (size_t)N_NODES * DIM * 2;      // 25.6 MB
  bf16*  qkv     = (bf16*)base;   base += (size_t)HALF_N * 1024 * 2;      // 51.2 MB
  bf16*  agg     = (bf16*)base;   base += (size_t)HALF_N * DIM * 2;       // 12.8 MB
  bf16*  attn_o  = (bf16*)base;   base += (size_t)HALF_N * DIM * 2;       // 12.8 MB
  bf16*  ffout   = (bf16*)base;   base += (size_t)N_NODES * DIM * 2;      // 25.6 MB
  bf16*  wt      = (bf16*)base;   base += (size_t)2 * WT_LAYER * 2;       // 4.5 MB
  float* biasq   = (float*)base;  base += 2048 * 4;
  int*   deg     = (int*)base;    base += HALF_N * 4;
  int*   ell     = (int*)base;    base += (size_t)HALF_N * MAXDEG * 4;    // 6.4 MB

  // one-time prep
  hipMemcpyAsync(nodes, x, (size_t)N_NODES * DIM * sizeof(float),
                 hipMemcpyDeviceToDevice, stream);
  prep_w<<<(2 * WT_LAYER + 255) / 256, 256, 0, stream>>>(Wq, Wkv, We, Wo, W1, W2, wt);
  prep_bias<<<8, 256, 0, stream>>>(bq, bkv, be, biasq);
  prep_x<<<(HALF_N * 64 + 255) / 256, 256, 0, stream>>>(x, A2);
  hipMemsetAsync(deg, 0, HALF_N * sizeof(int), stream);
  ell_build<<<(N_EDGES + 255) / 256, 256, 0, stream>>>(ei, deg, ell);

  const int GP_H = (HALF_N + 63) / 64;    // 391
  const int GP_N = (N_NODES + 63) / 64;   // 782

  for (int l = 0; l < NDEPTH; ++l) {
    const bf16* wl = wt + (size_t)l * WT_LAYER;
    if (l == 0)
      ln0_kernel<<<(HALF_N + 3) / 4, 256, 0, stream>>>(x, ln1_g, ln1_b, A2);
    // qkv|eB = [xn|x] @ qkveT + bias
    gemm_nloop<512, 8><<<GP_H, 256, 0, stream>>>(A2, wl + WT_QKVE, biasq + l * 1024, qkv, HALF_N);
    // attention gather (+eB)
    attn_gather<<<(HALF_N + 3) / 4, 256, 0, stream>>>(deg, ell, qkv, agg);
    // attn_out = agg @ Wo + bo
    gemm_nloop<256, 2><<<GP_H, 256, 0, stream>>>(agg, wl + WT_WO, bo + l * DIM, attn_o, HALF_N);
    // gr1 + ln2 (all rows)
    gr_ln<1, 0><<<(N_NODES + 3) / 4, 256, 0, stream>>>(
        attn_o, bo + l * DIM, nodes, g_attn + l * 768,
        ln2_g + l * DIM, ln2_b + l * DIM, xn_bf, DIM, N_NODES,
        nullptr, nullptr, nullptr, N_NODES, HALF_N, 0);
    // fused FF over all rows
    ff_fused<<<GP_N, 512, 0, stream>>>(xn_bf, wl + WT_W1, b1 + l * 1024,
                                       wl + WT_W2, b2 + l * DIM, ffout, N_NODES);
    if (l < NDEPTH - 1) {   // gr2 + ln1(next layer) into A2 left half
      gr_ln<1, 0><<<(N_NODES + 3) / 4, 256, 0, stream>>>(
          ffout, nullptr, nodes, g_ff + l * 768,
          ln1_g + (l + 1) * DIM, ln1_b + (l + 1) * DIM, A2, 512, HALF_N,
          nullptr, nullptr, nullptr, N_NODES, N_NODES, 0);
    } else {                // final: gr2 + output projection
      gr_ln<0, 1><<<(N_NODES + 3) / 4, 256, 0, stream>>>(
          ffout, nullptr, nodes, g_ff + l * 768,
          nullptr, nullptr, nullptr, 0, 0,
          Wout, bout, out, N_NODES, N_NODES, 0);
    }
  }
}